// Round 8
// baseline (230.600 us; speedup 1.0000x reference)
//
#include <hip/hip_runtime.h>
#include <hip/hip_bf16.h>

#define NB 4       // batch
#define SEQ 1024
#define EMB 1024
#define NH 16
#define HD 64

typedef unsigned short u16;
typedef __attribute__((ext_vector_type(8))) __bf16 bf16x8;
typedef __attribute__((ext_vector_type(8))) short short8;
typedef __attribute__((ext_vector_type(4))) float floatx4;

// fp32 -> bf16 round-to-nearest-even
__device__ inline u16 f2b_rn(float f) {
    union { float f; unsigned int i; } x; x.f = f;
    unsigned int r = (x.i + 0x7FFFu + ((x.i >> 16) & 1u)) >> 16;
    return (u16)r;
}
__device__ inline bf16x8 s2b(short8 v) {
    union { short8 s; bf16x8 b; } x; x.s = v; return x.b;
}

// async global->LDS, 16 B per lane.  LDS dest = wave-uniform base + lane*16.
__device__ inline void gload_lds16(const void* g, void* l) {
    __builtin_amdgcn_global_load_lds(
        (const __attribute__((address_space(1))) void*)g,
        (__attribute__((address_space(3))) void*)l, 16, 0, 0);
}

// XOR-swizzled fragment read from an unpadded [rows][64] u16 LDS buffer.
// One row = 128 B = all 32 banks; (r&7) XOR spreads 16-lane b128 reads.
__device__ inline bf16x8 ldsfrag(const u16* base, int r, int c) {
    return s2b(*(const short8*)&base[r * 64 + (c ^ ((r & 7) * 8))]);
}

__device__ inline void cvt8(const float* __restrict__ s, u16* __restrict__ d) {
    float4 a = *(const float4*)(s);
    float4 b = *(const float4*)(s + 4);
    union { u16 u[8]; int4 v; } o;
    o.u[0] = f2b_rn(a.x); o.u[1] = f2b_rn(a.y); o.u[2] = f2b_rn(a.z); o.u[3] = f2b_rn(a.w);
    o.u[4] = f2b_rn(b.x); o.u[5] = f2b_rn(b.y); o.u[6] = f2b_rn(b.z); o.u[7] = f2b_rn(b.w);
    *(int4*)(d) = o.v;
}

// ---------------------------------------------------------------------------
// Kernel P: fused prep.  blockIdx.x ranges:
//   [0,2048)      x fp32->bf16           (2048 elems/block)
//   [2048,2560)   Wo fp32->bf16
//   [2560,3328)   W transpose+convert -> Wt[3072][1024]
//   [3328,4352)   mask -> bitmask (64 wave-rows per block: 4 waves x 16 iters)
// ---------------------------------------------------------------------------
__global__ __launch_bounds__(256) void prep(
    const float* __restrict__ x, const float* __restrict__ Wq,
    const float* __restrict__ Wk, const float* __restrict__ Wv,
    const float* __restrict__ Wo, const int* __restrict__ mask,
    u16* __restrict__ xb, u16* __restrict__ Wt, u16* __restrict__ Wob,
    unsigned long long* __restrict__ bits)
{
    __shared__ u16 T[64 * 80];
    int bx = blockIdx.x;
    int tid = threadIdx.x;

    if (bx < 2048) {
        int i = bx * 2048 + tid * 8;
        cvt8(x + i, xb + i);
    } else if (bx < 2560) {
        int i = (bx - 2048) * 2048 + tid * 8;
        cvt8(Wo + i, Wob + i);
    } else if (bx < 3328) {
        int bx2 = bx - 2560;
        int e0 = (bx2 & 15) * 64;
        int ph = bx2 >> 4;              // 0..47
        int p = ph >> 4, h = ph & 15;
        const float* W = (p == 0 ? Wq : (p == 1 ? Wk : Wv)) + h * (EMB * HD);
        #pragma unroll
        for (int c = 0; c < 2; ++c) {
            int flat = c * 2048 + tid * 8;
            int r = flat >> 6;
            int d = flat & 63;
            cvt8(W + (size_t)(e0 + r) * HD + d, &T[r * 80 + d]);
        }
        __syncthreads();
        int d = tid >> 2;
        int ec = tid & 3;
        union { u16 u[16]; int4 v[2]; } tmp;
        #pragma unroll
        for (int i = 0; i < 16; ++i) tmp.u[i] = T[(ec * 16 + i) * 80 + d];
        u16* dst = Wt + ((size_t)(p * NH + h) * HD + d) * EMB + e0 + ec * 16;
        *(int4*)(dst) = tmp.v[0];
        *(int4*)(dst + 8) = tmp.v[1];
    } else {
        int base = (bx - 3328) * 64 + (tid >> 6) * 16;   // 4 waves x 16 rows
        int lane = tid & 63;
        #pragma unroll
        for (int i = 0; i < 16; ++i) {
            int gw = base + i;                            // 0..65535
            int m = mask[(size_t)gw * 64 + lane];
            unsigned long long bl = __ballot(m != 0);
            if (lane == 0) bits[gw] = bl;
        }
    }
}

// ---------------------------------------------------------------------------
// Kernel 1: fused QKV GEMM, m97 recipe (proven 48 us / 537 TF).
// C[4096][3072] = x @ Wt^T (+bias).  128x128 tile, BK=64, single buffer.
// Q scaled by log2(e)/8.  V written transposed: Vt[b,h][d][s].
// ---------------------------------------------------------------------------
__global__ __launch_bounds__(256) void qkv_gemm(
    const u16* __restrict__ x,    // bf16 [4096][1024]
    const u16* __restrict__ Wt2,  // bf16 [3072][1024]
    const float* __restrict__ bq, const float* __restrict__ bk, const float* __restrict__ bv,
    u16* __restrict__ Q, u16* __restrict__ K, u16* __restrict__ Vt)
{
    __shared__ u16 As[128 * 64];
    __shared__ u16 Bs[128 * 64];

    int m0 = blockIdx.x * 128;
    int n0 = blockIdx.y * 128;
    int tid = threadIdx.x;
    int w = tid >> 6, lane = tid & 63, quad = lane >> 4, ln = lane & 15;
    int wm = w & 1, wn = w >> 1;

    floatx4 acc[4][4] = {};

    for (int k0 = 0; k0 < EMB; k0 += 64) {
        __syncthreads();
        #pragma unroll
        for (int i = 0; i < 4; ++i) {
            int flat0 = i * 256 + (tid & 192);
            int flat = flat0 + lane;
            int r = flat >> 3;
            int c = ((flat & 7) ^ (r & 7)) * 8;
            gload_lds16(x   + (size_t)(m0 + r) * EMB + k0 + c, As + flat0 * 8);
            gload_lds16(Wt2 + (size_t)(n0 + r) * EMB + k0 + c, Bs + flat0 * 8);
        }
        __syncthreads();

        #pragma unroll
        for (int kk = 0; kk < 2; ++kk) {
            bf16x8 a[4], bf[4];
            #pragma unroll
            for (int mt = 0; mt < 4; ++mt)
                a[mt] = ldsfrag(As, wm * 64 + mt * 16 + ln, kk * 32 + quad * 8);
            #pragma unroll
            for (int nc = 0; nc < 4; ++nc)
                bf[nc] = ldsfrag(Bs, wn * 64 + nc * 16 + ln, kk * 32 + quad * 8);
            #pragma unroll
            for (int mt = 0; mt < 4; ++mt)
                #pragma unroll
                for (int nc = 0; nc < 4; ++nc)
                    acc[mt][nc] = __builtin_amdgcn_mfma_f32_16x16x32_bf16(a[mt], bf[nc], acc[mt][nc], 0, 0, 0);
        }
    }

    int p = n0 >> 10;
    const float* bias = (p == 0 ? bq : (p == 1 ? bk : bv));
    if (p < 2) {
        u16* Out = (p == 0) ? Q : K;
        float qs = (p == 0) ? 0.125f * 1.44269504f : 1.0f;   // fold 1/sqrt(64) and log2(e)
        #pragma unroll
        for (int nc = 0; nc < 4; ++nc) {
            int n = n0 + wn * 64 + nc * 16 + ln;
            int h = (n >> 6) & 15, d = n & 63;
            float bv_ = bias[n & 1023];
            #pragma unroll
            for (int mt = 0; mt < 4; ++mt) {
                #pragma unroll
                for (int reg = 0; reg < 4; ++reg) {
                    int m = m0 + wm * 64 + mt * 16 + quad * 4 + reg;
                    int b_ = m >> 10, s = m & 1023;
                    Out[((size_t)(b_ * NH + h) * SEQ + s) * HD + d] = f2b_rn((acc[mt][nc][reg] + bv_) * qs);
                }
            }
        }
    } else {
        #pragma unroll
        for (int nc = 0; nc < 4; ++nc) {
            int n = n0 + wn * 64 + nc * 16 + ln;
            int h = (n >> 6) & 15, d = n & 63;
            float bv_ = bias[n & 1023];
            #pragma unroll
            for (int mt = 0; mt < 4; ++mt) {
                int m = m0 + wm * 64 + mt * 16 + quad * 4;
                int b_ = m >> 10, s = m & 1023;
                union { u16 u[4]; uint2 v; } pk;
                #pragma unroll
                for (int reg = 0; reg < 4; ++reg)
                    pk.u[reg] = f2b_rn(acc[mt][nc][reg] + bv_);
                *(uint2*)&Vt[((size_t)(b_ * NH + h) * HD + d) * SEQ + s] = pk.v;
            }
        }
    }
}

// ---------------------------------------------------------------------------
// Kernel 2: flash attention v5 — BARRIER-FREE main loop.
// Block = 256 threads = 4 waves; one block per (b,h, 64-row q-tile).
// Each wave owns 4 of the 16 t-tiles and processes the FULL 64x64 S^T tile
// (K-frags amortized over 4 m-strips).  K/V staged into per-wave LDS with
// explicit s_waitcnt (no __syncthreads).  l = in-lane row-sum of exp2 + 2
// shuffles.  One barrier at the end to combine the 4 waves' partial O/l.
// Per-wave LDS: Ks 8KB + Vs 8KB + Ps(16x72) 2.25KB = 18.25KB; x4 = 73KB
// -> 2 blocks/CU.
// ---------------------------------------------------------------------------
__global__ __launch_bounds__(256) void attn(
    const u16* __restrict__ Q, const u16* __restrict__ K, const u16* __restrict__ Vt,
    const unsigned long long* __restrict__ bits,
    u16* __restrict__ Aout)         // bf16 [B][S][E]
{
    __shared__ u16 lds[4][9344];    // 18688 B per wave

    int q0 = blockIdx.x * 64;
    int bh = blockIdx.y;
    int b = bh >> 4, h = bh & 15;
    const u16* Qb = Q  + (size_t)bh * SEQ * HD;
    const u16* Kb = K  + (size_t)bh * SEQ * HD;
    const u16* Vb = Vt + (size_t)bh * HD * SEQ;   // [d][s]

    int tid = threadIdx.x;
    int w = tid >> 6, lane = tid & 63, quad = lane >> 4, ln = lane & 15;

    u16* KsW = &lds[w][0];      // [64 t][64 d], swizzled
    u16* VsW = &lds[w][4096];   // [64 d][64 t], swizzled
    u16* PsW = &lds[w][8192];   // [16 m][stride 72] per strip, natural layout

    // Q B-fragments for all 4 m-strips (col m = mc*16+ln), reused all tiles
    bf16x8 qf[4][2];
    #pragma unroll
    for (int mc = 0; mc < 4; ++mc) {
        const u16* qp = Qb + (size_t)(q0 + mc * 16 + ln) * HD + quad * 8;
        union { int4 i; bf16x8 b; } c0, c1;
        c0.i = *(const int4*)(qp);
        c1.i = *(const int4*)(qp + 32);
        qf[mc][0] = c0.b; qf[mc][1] = c1.b;
    }

    floatx4 o[4][4] = {};                 // [mc][dt] partial O (C-layout)
    float l_acc[4] = {0.f, 0.f, 0.f, 0.f};

    for (int ti = 0; ti < 4; ++ti) {
        int tt = w * 4 + ti;
        int t0 = tt * 64;
        // previous tile's LDS reads done before DMA overwrites; also drains
        // any prior vmem.  Wave-local: no barrier.
        __builtin_amdgcn_s_waitcnt(0);
        #pragma unroll
        for (int i = 0; i < 8; ++i) {
            int flat = i * 64 + lane;
            int r = flat >> 3;
            int c = ((flat & 7) ^ (r & 7)) * 8;
            gload_lds16(Kb + (size_t)(t0 + r) * HD + c, KsW + i * 512);
            gload_lds16(Vb + (size_t)r * SEQ + t0 + c, VsW + i * 512);
        }
        __builtin_amdgcn_s_waitcnt(0);    // staging landed

        // S^T = K Q^T : full 64t x 64m tile
        floatx4 sc[4][4] = {};            // [tb][mc]
        #pragma unroll
        for (int kk = 0; kk < 2; ++kk) {
            bf16x8 kf[4];
            #pragma unroll
            for (int tb = 0; tb < 4; ++tb)
                kf[tb] = ldsfrag(KsW, tb * 16 + ln, kk * 32 + quad * 8);
            #pragma unroll
            for (int tb = 0; tb < 4; ++tb)
                #pragma unroll
                for (int mc = 0; mc < 4; ++mc)
                    sc[tb][mc] = __builtin_amdgcn_mfma_f32_16x16x32_bf16(
                        kf[tb], qf[mc][kk], sc[tb][mc], 0, 0, 0);
        }

        // mask: lane's column m = mc*16+ln; bit j = col t0+j valid
        #pragma unroll
        for (int mc = 0; mc < 4; ++mc) {
            unsigned long long bm = bits[((size_t)b * SEQ + q0 + mc * 16 + ln) * 16 + tt];
            if (__any(bm != ~0ull)) {
                #pragma unroll
                for (int tb = 0; tb < 4; ++tb)
                    #pragma unroll
                    for (int reg = 0; reg < 4; ++reg)
                        if (!((bm >> (tb * 16 + quad * 4 + reg)) & 1)) sc[tb][mc][reg] = -1e30f;
            }
        }

        // V^T fragments (shared across the 4 m-strips)
        bf16x8 vf[2][4];
        #pragma unroll
        for (int kk = 0; kk < 2; ++kk)
            #pragma unroll
            for (int dt = 0; dt < 4; ++dt)
                vf[kk][dt] = ldsfrag(VsW, dt * 16 + ln, kk * 32 + quad * 8);

        // per m-strip: exp2 + l + P roundtrip + PV
        #pragma unroll
        for (int mc = 0; mc < 4; ++mc) {
            float lp = 0.f;
            #pragma unroll
            for (int tb = 0; tb < 4; ++tb) {
                union { float f; unsigned int i; } e0_, e1_, e2_, e3_;
                e0_.f = __builtin_amdgcn_exp2f(sc[tb][mc][0]);
                e1_.f = __builtin_amdgcn_exp2f(sc[tb][mc][1]);
                e2_.f = __builtin_amdgcn_exp2f(sc[tb][mc][2]);
                e3_.f = __builtin_amdgcn_exp2f(sc[tb][mc][3]);
                lp += (e0_.f + e1_.f) + (e2_.f + e3_.f);
                uint2 pk;
                pk.x = ((e0_.i + 0x8000u) >> 16) | ((e1_.i + 0x8000u) & 0xFFFF0000u);
                pk.y = ((e2_.i + 0x8000u) >> 16) | ((e3_.i + 0x8000u) & 0xFFFF0000u);
                *(uint2*)&PsW[ln * 72 + tb * 16 + quad * 4] = pk;
            }
            // sum across the 4 quads (each holds 16 of the 64 t's)
            lp += __shfl_xor(lp, 16, 64);
            lp += __shfl_xor(lp, 32, 64);
            l_acc[mc] += lp;

            #pragma unroll
            for (int kk = 0; kk < 2; ++kk) {
                bf16x8 pf = s2b(*(const short8*)&PsW[ln * 72 + kk * 32 + quad * 8]);
                #pragma unroll
                for (int dt = 0; dt < 4; ++dt)
                    o[mc][dt] = __builtin_amdgcn_mfma_f32_16x16x32_bf16(
                        pf, vf[kk][dt], o[mc][dt], 0, 0, 0);
            }
        }
    }

    // ---- combine: each wave holds partial O/l over its 4 t-tiles ----
    float* dump = (float*)&lds[w][0];    // 17 frags x 64 lanes x 16B = 17408 B
    #pragma unroll
    for (int mc = 0; mc < 4; ++mc)
        #pragma unroll
        for (int dt = 0; dt < 4; ++dt)
            *(floatx4*)&dump[((mc * 4 + dt) * 64 + lane) * 4] = o[mc][dt];
    {
        floatx4 lv; lv[0] = l_acc[0]; lv[1] = l_acc[1]; lv[2] = l_acc[2]; lv[3] = l_acc[3];
        *(floatx4*)&dump[(16 * 64 + lane) * 4] = lv;
    }
    __syncthreads();

    // wave w reduces strip mc = w
    floatx4 osum[4] = {};
    floatx4 lsumv = {};
    #pragma unroll
    for (int wp = 0; wp < 4; ++wp) {
        const float* src = (const float*)&lds[wp][0];
        #pragma unroll
        for (int dt = 0; dt < 4; ++dt)
            osum[dt] += *(const floatx4*)&src[((w * 4 + dt) * 64 + lane) * 4];
        lsumv += *(const floatx4*)&src[(16 * 64 + lane) * 4];
    }
    float l_m = lsumv[w];   // full l for q-row m = w*16 + ln

    // redistribute l (held per (ln) -> needed per (quad*4+reg)) via small LDS
    float* Lb = (float*)((char*)&lds[w][0] + 17408);
    if (quad == 0) Lb[ln] = l_m;
    #pragma unroll
    for (int reg = 0; reg < 4; ++reg) {
        float inv = 1.0f / Lb[quad * 4 + reg];
        int m = q0 + w * 16 + quad * 4 + reg;
        #pragma unroll
        for (int dt = 0; dt < 4; ++dt)
            Aout[((size_t)b * SEQ + m) * EMB + h * HD + dt * 16 + ln] = f2b_rn(osum[dt][reg] * inv);
    }
}

// ---------------------------------------------------------------------------
// Kernel 3: output projection.  64x128 tile, BK=64 single buffer, grid 512
// (2 blocks/CU).  Out[4096][1024] fp32.
// ---------------------------------------------------------------------------
__global__ __launch_bounds__(256) void out_proj(
    const u16* __restrict__ A,    // bf16 [4096][1024]
    const u16* __restrict__ Wo,   // bf16 [1024][1024] (n,k)
    const float* __restrict__ bo,
    float* __restrict__ Out)
{
    __shared__ u16 As[64 * 64];
    __shared__ u16 Bs[128 * 64];

    int m0 = blockIdx.x * 64;
    int n0 = blockIdx.y * 128;
    int tid = threadIdx.x;
    int w = tid >> 6, lane = tid & 63, quad = lane >> 4, ln = lane & 15;
    int wm = w & 1, wn = w >> 1;

    floatx4 acc[2][4] = {};

    for (int k0 = 0; k0 < EMB; k0 += 64) {
        __syncthreads();
        #pragma unroll
        for (int i = 0; i < 2; ++i) {
            int flat0 = i * 256 + (tid & 192);
            int flat = flat0 + lane;
            int r = flat >> 3;                   // 0..63
            int c = ((flat & 7) ^ (r & 7)) * 8;
            gload_lds16(A + (size_t)(m0 + r) * EMB + k0 + c, As + flat0 * 8);
        }
        #pragma unroll
        for (int i = 0; i < 4; ++i) {
            int flat0 = i * 256 + (tid & 192);
            int flat = flat0 + lane;
            int r = flat >> 3;                   // 0..127
            int c = ((flat & 7) ^ (r & 7)) * 8;
            gload_lds16(Wo + (size_t)(n0 + r) * EMB + k0 + c, Bs + flat0 * 8);
        }
        __syncthreads();

        #pragma unroll
        for (int kk = 0; kk < 2; ++kk) {
            bf16x8 a[2], bfr[4];
            #pragma unroll
            for (int mt = 0; mt < 2; ++mt)
                a[mt] = ldsfrag(As, wm * 32 + mt * 16 + ln, kk * 32 + quad * 8);
            #pragma unroll
            for (int nc = 0; nc < 4; ++nc)
                bfr[nc] = ldsfrag(Bs, wn * 64 + nc * 16 + ln, kk * 32 + quad * 8);
            #pragma unroll
            for (int mt = 0; mt < 2; ++mt)
                #pragma unroll
                for (int nc = 0; nc < 4; ++nc)
                    acc[mt][nc] = __builtin_amdgcn_mfma_f32_16x16x32_bf16(a[mt], bfr[nc], acc[mt][nc], 0, 0, 0);
        }
    }

    #pragma unroll
    for (int nc = 0; nc < 4; ++nc) {
        int n = n0 + wn * 64 + nc * 16 + ln;
        float bb = bo[n];
        #pragma unroll
        for (int mt = 0; mt < 2; ++mt) {
            #pragma unroll
            for (int reg = 0; reg < 4; ++reg) {
                int m = m0 + wm * 32 + mt * 16 + quad * 4 + reg;
                Out[(size_t)m * EMB + n] = acc[mt][nc][reg] + bb;
            }
        }
    }
}

// ---------------------------------------------------------------------------
extern "C" void kernel_launch(void* const* d_in, const int* in_sizes, int n_in,
                              void* d_out, int out_size, void* d_ws, size_t ws_size,
                              hipStream_t stream) {
    const float* x  = (const float*)d_in[0];
    const int*   mk = (const int*)d_in[1];
    const float* Wq = (const float*)d_in[2];
    const float* bq = (const float*)d_in[3];
    const float* Wk = (const float*)d_in[4];
    const float* bk = (const float*)d_in[5];
    const float* Wv = (const float*)d_in[6];
    const float* bv = (const float*)d_in[7];
    const float* Wo = (const float*)d_in[8];
    const float* bo = (const float*)d_in[9];
    float* out = (float*)d_out;

    const size_t MB = 1u << 20;
    char* ws = (char*)d_ws;
    u16* xb  = (u16*)ws;                                   // [ 0, 8M)
    u16* Wt  = (u16*)(ws + 8 * MB);                        // [ 8,14M)
    u16* Wob = (u16*)(ws + 14 * MB);                       // [14,16M)
    unsigned long long* bits = (unsigned long long*)(ws + 16 * MB); // [16,16.5M)
    u16* Qw  = (u16*)(ws + 16 * MB + 512 * 1024);          // [16.5,24.5M)
    u16* Kw  = (u16*)(ws + 24 * MB + 512 * 1024);          // [24.5,32.5M)
    u16* Vtw = (u16*)(ws + 32 * MB + 512 * 1024);          // [32.5,40.5M)
    u16* Ao  = xb;                                         // reuse: xb dead after qkv

    prep<<<4352, 256, 0, stream>>>(x, Wq, Wk, Wv, Wo, mk, xb, Wt, Wob, bits);
    qkv_gemm<<<dim3((NB * SEQ) / 128, 3 * EMB / 128), 256, 0, stream>>>(
        xb, Wt, bq, bk, bv, Qw, Kw, Vtw);
    attn<<<dim3(SEQ / 64, NB * NH), 256, 0, stream>>>(Qw, Kw, Vtw, bits, Ao);
    out_proj<<<dim3((NB * SEQ) / 64, EMB / 128), 256, 0, stream>>>(Ao, Wob, bo, out);
}

// Round 9
// 211.453 us; speedup vs baseline: 1.0906x; 1.0906x over previous
//
#include <hip/hip_runtime.h>
#include <hip/hip_bf16.h>

#define NB 4       // batch
#define SEQ 1024
#define EMB 1024
#define NH 16
#define HD 64

typedef unsigned short u16;
typedef __attribute__((ext_vector_type(8))) __bf16 bf16x8;
typedef __attribute__((ext_vector_type(8))) short short8;
typedef __attribute__((ext_vector_type(4))) float floatx4;

// fp32 -> bf16 round-to-nearest-even
__device__ inline u16 f2b_rn(float f) {
    union { float f; unsigned int i; } x; x.f = f;
    unsigned int r = (x.i + 0x7FFFu + ((x.i >> 16) & 1u)) >> 16;
    return (u16)r;
}
__device__ inline bf16x8 s2b(short8 v) {
    union { short8 s; bf16x8 b; } x; x.s = v; return x.b;
}

// async global->LDS, 16 B per lane.  LDS dest = wave-uniform base + lane*16.
__device__ inline void gload_lds16(const void* g, void* l) {
    __builtin_amdgcn_global_load_lds(
        (const __attribute__((address_space(1))) void*)g,
        (__attribute__((address_space(3))) void*)l, 16, 0, 0);
}

// XOR-swizzled fragment read from an unpadded [rows][64] u16 LDS buffer.
// One row = 128 B = all 32 banks; (r&7) XOR spreads 16-lane b128 reads.
__device__ inline bf16x8 ldsfrag(const u16* base, int r, int c) {
    return s2b(*(const short8*)&base[r * 64 + (c ^ ((r & 7) * 8))]);
}

__device__ inline void cvt8(const float* __restrict__ s, u16* __restrict__ d) {
    float4 a = *(const float4*)(s);
    float4 b = *(const float4*)(s + 4);
    union { u16 u[8]; int4 v; } o;
    o.u[0] = f2b_rn(a.x); o.u[1] = f2b_rn(a.y); o.u[2] = f2b_rn(a.z); o.u[3] = f2b_rn(a.w);
    o.u[4] = f2b_rn(b.x); o.u[5] = f2b_rn(b.y); o.u[6] = f2b_rn(b.z); o.u[7] = f2b_rn(b.w);
    *(int4*)(d) = o.v;
}

// ---------------------------------------------------------------------------
// Kernel P: prep (shrunk).  blockIdx.x ranges:
//   [0,2048)      x fp32->bf16           (2048 elems/block)
//   [2048,2816)   W transpose+convert -> Wt[3072][1024]
// (Wo-convert and mask-ballot moved into qkv_gemm's grid — independent work.)
// ---------------------------------------------------------------------------
__global__ __launch_bounds__(256) void prep(
    const float* __restrict__ x, const float* __restrict__ Wq,
    const float* __restrict__ Wk, const float* __restrict__ Wv,
    u16* __restrict__ xb, u16* __restrict__ Wt)
{
    __shared__ u16 T[64 * 80];
    int bx = blockIdx.x;
    int tid = threadIdx.x;

    if (bx < 2048) {
        int i = bx * 2048 + tid * 8;
        cvt8(x + i, xb + i);
    } else {
        int bx2 = bx - 2048;
        int e0 = (bx2 & 15) * 64;
        int ph = bx2 >> 4;              // 0..47
        int p = ph >> 4, h = ph & 15;
        const float* W = (p == 0 ? Wq : (p == 1 ? Wk : Wv)) + h * (EMB * HD);
        #pragma unroll
        for (int c = 0; c < 2; ++c) {
            int flat = c * 2048 + tid * 8;
            int r = flat >> 6;
            int d = flat & 63;
            cvt8(W + (size_t)(e0 + r) * HD + d, &T[r * 80 + d]);
        }
        __syncthreads();
        int d = tid >> 2;
        int ec = tid & 3;
        union { u16 u[16]; int4 v[2]; } tmp;
        #pragma unroll
        for (int i = 0; i < 16; ++i) tmp.u[i] = T[(ec * 16 + i) * 80 + d];
        u16* dst = Wt + ((size_t)(p * NH + h) * HD + d) * EMB + e0 + ec * 16;
        *(int4*)(dst) = tmp.v[0];
        *(int4*)(dst + 8) = tmp.v[1];
    }
}

// ---------------------------------------------------------------------------
// Kernel 1: fused QKV GEMM (m97 recipe, proven 48 us) + aux tail blocks.
// gid < 768 :  C[4096][3072] = x @ Wt^T (+bias); 128x128 tile, BK=64.
//              Q scaled by log2(e)/8.  V written transposed Vt[b,h][d][s].
// gid 768..1279 : Wo fp32->bf16 (independent of GEMM, fills scheduler shadow)
// gid 1280..1535: mask -> bitmask ballots
// ---------------------------------------------------------------------------
__global__ __launch_bounds__(256) void qkv_gemm(
    const u16* __restrict__ x,    // bf16 [4096][1024]
    const u16* __restrict__ Wt2,  // bf16 [3072][1024]
    const float* __restrict__ bq, const float* __restrict__ bk, const float* __restrict__ bv,
    const float* __restrict__ Wo, const int* __restrict__ mask,
    u16* __restrict__ Q, u16* __restrict__ K, u16* __restrict__ Vt,
    u16* __restrict__ Wob, unsigned long long* __restrict__ bits)
{
    __shared__ u16 As[128 * 64];
    __shared__ u16 Bs[128 * 64];

    int gid = blockIdx.x;
    int tid = threadIdx.x;

    if (gid >= 768) {
        if (gid < 1280) {                 // Wo convert: 512 blocks x 2048 elems
            int i = (gid - 768) * 2048 + tid * 8;
            cvt8(Wo + i, Wob + i);
        } else {                          // mask ballots: 256 blocks x 256 rows
            int base = (gid - 1280) * 256 + (tid >> 6) * 64;
            int lane = tid & 63;
            for (int i = 0; i < 64; ++i) {
                int gw = base + i;        // 0..65535
                int m = mask[(size_t)gw * 64 + lane];
                unsigned long long bl = __ballot(m != 0);
                if (lane == 0) bits[gw] = bl;
            }
        }
        return;
    }

    int m0 = (gid & 31) * 128;
    int n0 = (gid >> 5) * 128;
    int w = tid >> 6, lane = tid & 63, quad = lane >> 4, ln = lane & 15;
    int wm = w & 1, wn = w >> 1;

    floatx4 acc[4][4] = {};

    for (int k0 = 0; k0 < EMB; k0 += 64) {
        __syncthreads();
        #pragma unroll
        for (int i = 0; i < 4; ++i) {
            int flat0 = i * 256 + (tid & 192);
            int flat = flat0 + lane;
            int r = flat >> 3;
            int c = ((flat & 7) ^ (r & 7)) * 8;
            gload_lds16(x   + (size_t)(m0 + r) * EMB + k0 + c, As + flat0 * 8);
            gload_lds16(Wt2 + (size_t)(n0 + r) * EMB + k0 + c, Bs + flat0 * 8);
        }
        __syncthreads();

        #pragma unroll
        for (int kk = 0; kk < 2; ++kk) {
            bf16x8 a[4], bf[4];
            #pragma unroll
            for (int mt = 0; mt < 4; ++mt)
                a[mt] = ldsfrag(As, wm * 64 + mt * 16 + ln, kk * 32 + quad * 8);
            #pragma unroll
            for (int nc = 0; nc < 4; ++nc)
                bf[nc] = ldsfrag(Bs, wn * 64 + nc * 16 + ln, kk * 32 + quad * 8);
            #pragma unroll
            for (int mt = 0; mt < 4; ++mt)
                #pragma unroll
                for (int nc = 0; nc < 4; ++nc)
                    acc[mt][nc] = __builtin_amdgcn_mfma_f32_16x16x32_bf16(a[mt], bf[nc], acc[mt][nc], 0, 0, 0);
        }
    }

    int p = n0 >> 10;
    const float* bias = (p == 0 ? bq : (p == 1 ? bk : bv));
    if (p < 2) {
        u16* Out = (p == 0) ? Q : K;
        float qs = (p == 0) ? 0.125f * 1.44269504f : 1.0f;   // fold 1/sqrt(64) and log2(e)
        #pragma unroll
        for (int nc = 0; nc < 4; ++nc) {
            int n = n0 + wn * 64 + nc * 16 + ln;
            int h = (n >> 6) & 15, d = n & 63;
            float bv_ = bias[n & 1023];
            #pragma unroll
            for (int mt = 0; mt < 4; ++mt) {
                #pragma unroll
                for (int reg = 0; reg < 4; ++reg) {
                    int m = m0 + wm * 64 + mt * 16 + quad * 4 + reg;
                    int b_ = m >> 10, s = m & 1023;
                    Out[((size_t)(b_ * NH + h) * SEQ + s) * HD + d] = f2b_rn((acc[mt][nc][reg] + bv_) * qs);
                }
            }
        }
    } else {
        #pragma unroll
        for (int nc = 0; nc < 4; ++nc) {
            int n = n0 + wn * 64 + nc * 16 + ln;
            int h = (n >> 6) & 15, d = n & 63;
            float bv_ = bias[n & 1023];
            #pragma unroll
            for (int mt = 0; mt < 4; ++mt) {
                int m = m0 + wm * 64 + mt * 16 + quad * 4;
                int b_ = m >> 10, s = m & 1023;
                union { u16 u[4]; uint2 v; } pk;
                #pragma unroll
                for (int reg = 0; reg < 4; ++reg)
                    pk.u[reg] = f2b_rn(acc[mt][nc][reg] + bv_);
                *(uint2*)&Vt[((size_t)(b_ * NH + h) * HD + d) * SEQ + s] = pk.v;
            }
        }
    }
}

// ---------------------------------------------------------------------------
// Kernel 2: flash attention v3 (verbatim r5 revert — best measured variant).
// Block = 128 threads = 2 waves; one block per (b,h, 64-row q-tile).
// Wave owns 2 strips of 16 q-rows.  S computed TRANSPOSED (S^T = K Q^T):
// lane owns one softmax column, in-lane reductions, packed P writes.
// No online max: Q carries log2e/8, P = exp2(s); l from a ones-row in V.
// ---------------------------------------------------------------------------
__global__ __launch_bounds__(128) void attn(
    const u16* __restrict__ Q, const u16* __restrict__ K, const u16* __restrict__ Vt,
    const unsigned long long* __restrict__ bits,
    u16* __restrict__ Aout)         // bf16 [B][S][E]
{
    const int PP = 72;  // Ps row stride in u16 (144 B)
    __shared__ u16 Ks[64 * 64];
    __shared__ u16 Vs[80 * 64];     // rows 0..63 = V^T tile, row 64 = ones
    __shared__ u16 Ps[64 * PP];

    int q0 = blockIdx.x * 64;
    int bh = blockIdx.y;
    int b = bh >> 4, h = bh & 15;
    const u16* Qb = Q  + (size_t)bh * SEQ * HD;
    const u16* Kb = K  + (size_t)bh * SEQ * HD;
    const u16* Vb = Vt + (size_t)bh * HD * SEQ;   // [d][s]

    int tid = threadIdx.x;
    int w = tid >> 6, lane = tid & 63, quad = lane >> 4, ln = lane & 15;

    if (tid < 16) *(uint2*)&Vs[64 * 64 + tid * 4] = make_uint2(0x3F803F80u, 0x3F803F80u);

    bf16x8 qf[2][2];
    #pragma unroll
    for (int s = 0; s < 2; ++s) {
        const u16* qp = Qb + (size_t)(q0 + w * 32 + s * 16 + ln) * HD + quad * 8;
        union { int4 i; bf16x8 b; } c0, c1;
        c0.i = *(const int4*)(qp);
        c1.i = *(const int4*)(qp + 32);
        qf[s][0] = c0.b; qf[s][1] = c1.b;
    }

    floatx4 o[2][5] = {};   // [strip][dt], dt=4 is the l column

    for (int tt = 0; tt < SEQ / 64; ++tt) {
        int t0 = tt * 64;
        __syncthreads();
        #pragma unroll
        for (int i = 0; i < 4; ++i) {
            int flat0 = i * 128 + (tid & 64);
            int flat = flat0 + lane;
            int r = flat >> 3;
            int c = ((flat & 7) ^ (r & 7)) * 8;
            gload_lds16(Kb + (size_t)(t0 + r) * HD + c, Ks + flat0 * 8);
            gload_lds16(Vb + (size_t)r * SEQ + t0 + c, Vs + flat0 * 8);
        }
        __syncthreads();

        // S^T = K Q^T : rows t, cols m
        floatx4 sc[2][4] = {};
        #pragma unroll
        for (int kk = 0; kk < 2; ++kk) {
            bf16x8 kf[4];
            #pragma unroll
            for (int tb = 0; tb < 4; ++tb)
                kf[tb] = ldsfrag(Ks, tb * 16 + ln, kk * 32 + quad * 8);
            #pragma unroll
            for (int s = 0; s < 2; ++s)
                #pragma unroll
                for (int tb = 0; tb < 4; ++tb)
                    sc[s][tb] = __builtin_amdgcn_mfma_f32_16x16x32_bf16(kf[tb], qf[s][kk], sc[s][tb], 0, 0, 0);
        }

        #pragma unroll
        for (int s = 0; s < 2; ++s) {
            unsigned long long bm = bits[((size_t)b * SEQ + q0 + w * 32 + s * 16 + ln) * 16 + tt];
            if (__any(bm != ~0ull)) {
                #pragma unroll
                for (int tb = 0; tb < 4; ++tb)
                    #pragma unroll
                    for (int reg = 0; reg < 4; ++reg)
                        if (!((bm >> (tb * 16 + quad * 4 + reg)) & 1)) sc[s][tb][reg] = -1e30f;
            }
        }

        // P = exp2(S), pack 4 consecutive t -> b64 LDS write
        #pragma unroll
        for (int s = 0; s < 2; ++s) {
            int mrow = w * 32 + s * 16 + ln;
            #pragma unroll
            for (int tb = 0; tb < 4; ++tb) {
                union { float f; unsigned int i; } e0_, e1_, e2_, e3_;
                e0_.f = __builtin_amdgcn_exp2f(sc[s][tb][0]);
                e1_.f = __builtin_amdgcn_exp2f(sc[s][tb][1]);
                e2_.f = __builtin_amdgcn_exp2f(sc[s][tb][2]);
                e3_.f = __builtin_amdgcn_exp2f(sc[s][tb][3]);
                uint2 pk;
                pk.x = ((e0_.i + 0x8000u) >> 16) | ((e1_.i + 0x8000u) & 0xFFFF0000u);
                pk.y = ((e2_.i + 0x8000u) >> 16) | ((e3_.i + 0x8000u) & 0xFFFF0000u);
                *(uint2*)&Ps[mrow * PP + tb * 16 + quad * 4] = pk;
            }
        }

        // O += P V  (l accumulates in dt=4 via the ones row)
        #pragma unroll
        for (int kk = 0; kk < 2; ++kk) {
            bf16x8 vf[5];
            #pragma unroll
            for (int dt = 0; dt < 5; ++dt)
                vf[dt] = ldsfrag(Vs, dt * 16 + ln, kk * 32 + quad * 8);
            #pragma unroll
            for (int s = 0; s < 2; ++s) {
                bf16x8 pf = s2b(*(const short8*)&Ps[(w * 32 + s * 16 + ln) * PP + kk * 32 + quad * 8]);
                #pragma unroll
                for (int dt = 0; dt < 5; ++dt)
                    o[s][dt] = __builtin_amdgcn_mfma_f32_16x16x32_bf16(pf, vf[dt], o[s][dt], 0, 0, 0);
            }
        }
    }

    #pragma unroll
    for (int s = 0; s < 2; ++s) {
        #pragma unroll
        for (int reg = 0; reg < 4; ++reg) {
            float l = __shfl(o[s][4][reg], lane & 48, 64);
            float inv = 1.0f / l;
            int m = q0 + w * 32 + s * 16 + quad * 4 + reg;
            #pragma unroll
            for (int dt = 0; dt < 4; ++dt)
                Aout[((size_t)b * SEQ + m) * EMB + h * HD + dt * 16 + ln] = f2b_rn(o[s][dt][reg] * inv);
        }
    }
}

// ---------------------------------------------------------------------------
// Kernel 3: output projection.  64x128 tile, BK=64 single buffer, grid 512
// (2 blocks/CU).  Out[4096][1024] fp32.
// ---------------------------------------------------------------------------
__global__ __launch_bounds__(256) void out_proj(
    const u16* __restrict__ A,    // bf16 [4096][1024]
    const u16* __restrict__ Wo,   // bf16 [1024][1024] (n,k)
    const float* __restrict__ bo,
    float* __restrict__ Out)
{
    __shared__ u16 As[64 * 64];
    __shared__ u16 Bs[128 * 64];

    int m0 = blockIdx.x * 64;
    int n0 = blockIdx.y * 128;
    int tid = threadIdx.x;
    int w = tid >> 6, lane = tid & 63, quad = lane >> 4, ln = lane & 15;
    int wm = w & 1, wn = w >> 1;

    floatx4 acc[2][4] = {};

    for (int k0 = 0; k0 < EMB; k0 += 64) {
        __syncthreads();
        #pragma unroll
        for (int i = 0; i < 2; ++i) {
            int flat0 = i * 256 + (tid & 192);
            int flat = flat0 + lane;
            int r = flat >> 3;                   // 0..63
            int c = ((flat & 7) ^ (r & 7)) * 8;
            gload_lds16(A + (size_t)(m0 + r) * EMB + k0 + c, As + flat0 * 8);
        }
        #pragma unroll
        for (int i = 0; i < 4; ++i) {
            int flat0 = i * 256 + (tid & 192);
            int flat = flat0 + lane;
            int r = flat >> 3;                   // 0..127
            int c = ((flat & 7) ^ (r & 7)) * 8;
            gload_lds16(Wo + (size_t)(n0 + r) * EMB + k0 + c, Bs + flat0 * 8);
        }
        __syncthreads();

        #pragma unroll
        for (int kk = 0; kk < 2; ++kk) {
            bf16x8 a[2], bfr[4];
            #pragma unroll
            for (int mt = 0; mt < 2; ++mt)
                a[mt] = ldsfrag(As, wm * 32 + mt * 16 + ln, kk * 32 + quad * 8);
            #pragma unroll
            for (int nc = 0; nc < 4; ++nc)
                bfr[nc] = ldsfrag(Bs, wn * 64 + nc * 16 + ln, kk * 32 + quad * 8);
            #pragma unroll
            for (int mt = 0; mt < 2; ++mt)
                #pragma unroll
                for (int nc = 0; nc < 4; ++nc)
                    acc[mt][nc] = __builtin_amdgcn_mfma_f32_16x16x32_bf16(a[mt], bfr[nc], acc[mt][nc], 0, 0, 0);
        }
    }

    #pragma unroll
    for (int nc = 0; nc < 4; ++nc) {
        int n = n0 + wn * 64 + nc * 16 + ln;
        float bb = bo[n];
        #pragma unroll
        for (int mt = 0; mt < 2; ++mt) {
            #pragma unroll
            for (int reg = 0; reg < 4; ++reg) {
                int m = m0 + wm * 32 + mt * 16 + quad * 4 + reg;
                Out[(size_t)m * EMB + n] = acc[mt][nc][reg] + bb;
            }
        }
    }
}

// ---------------------------------------------------------------------------
extern "C" void kernel_launch(void* const* d_in, const int* in_sizes, int n_in,
                              void* d_out, int out_size, void* d_ws, size_t ws_size,
                              hipStream_t stream) {
    const float* x  = (const float*)d_in[0];
    const int*   mk = (const int*)d_in[1];
    const float* Wq = (const float*)d_in[2];
    const float* bq = (const float*)d_in[3];
    const float* Wk = (const float*)d_in[4];
    const float* bk = (const float*)d_in[5];
    const float* Wv = (const float*)d_in[6];
    const float* bv = (const float*)d_in[7];
    const float* Wo = (const float*)d_in[8];
    const float* bo = (const float*)d_in[9];
    float* out = (float*)d_out;

    const size_t MB = 1u << 20;
    char* ws = (char*)d_ws;
    u16* xb  = (u16*)ws;                                   // [ 0, 8M)
    u16* Wt  = (u16*)(ws + 8 * MB);                        // [ 8,14M)
    u16* Wob = (u16*)(ws + 14 * MB);                       // [14,16M)
    unsigned long long* bits = (unsigned long long*)(ws + 16 * MB); // [16,16.5M)
    u16* Qw  = (u16*)(ws + 16 * MB + 512 * 1024);          // [16.5,24.5M)
    u16* Kw  = (u16*)(ws + 24 * MB + 512 * 1024);          // [24.5,32.5M)
    u16* Vtw = (u16*)(ws + 32 * MB + 512 * 1024);          // [32.5,40.5M)
    u16* Ao  = xb;                                         // reuse: xb dead after qkv

    prep<<<2816, 256, 0, stream>>>(x, Wq, Wk, Wv, xb, Wt);
    qkv_gemm<<<1536, 256, 0, stream>>>(
        xb, Wt, bq, bk, bv, Wo, mk, Qw, Kw, Vtw, Wob, bits);
    attn<<<dim3(SEQ / 64, NB * NH), 128, 0, stream>>>(Qw, Kw, Vtw, bits, Ao);
    out_proj<<<dim3((NB * SEQ) / 64, EMB / 128), 256, 0, stream>>>(Ao, Wob, bo, out);
}

// Round 10
// 200.836 us; speedup vs baseline: 1.1482x; 1.0529x over previous
//
#include <hip/hip_runtime.h>
#include <hip/hip_bf16.h>

#define NB 4       // batch
#define SEQ 1024
#define EMB 1024
#define NH 16
#define HD 64

typedef unsigned short u16;
typedef __attribute__((ext_vector_type(8))) __bf16 bf16x8;
typedef __attribute__((ext_vector_type(8))) short short8;
typedef __attribute__((ext_vector_type(4))) float floatx4;

// fp32 -> bf16 round-to-nearest-even
__device__ inline u16 f2b_rn(float f) {
    union { float f; unsigned int i; } x; x.f = f;
    unsigned int r = (x.i + 0x7FFFu + ((x.i >> 16) & 1u)) >> 16;
    return (u16)r;
}
__device__ inline bf16x8 s2b(short8 v) {
    union { short8 s; bf16x8 b; } x; x.s = v; return x.b;
}

// async global->LDS, 16 B per lane.  LDS dest = wave-uniform base + lane*16.
__device__ inline void gload_lds16(const void* g, void* l) {
    __builtin_amdgcn_global_load_lds(
        (const __attribute__((address_space(1))) void*)g,
        (__attribute__((address_space(3))) void*)l, 16, 0, 0);
}

// XOR-swizzled fragment read from an unpadded [rows][64] u16 LDS buffer.
// One row = 128 B = all 32 banks; (r&7) XOR spreads 16-lane b128 reads.
__device__ inline bf16x8 ldsfrag(const u16* base, int r, int c) {
    return s2b(*(const short8*)&base[r * 64 + (c ^ ((r & 7) * 8))]);
}

__device__ inline void cvt8(const float* __restrict__ s, u16* __restrict__ d) {
    float4 a = *(const float4*)(s);
    float4 b = *(const float4*)(s + 4);
    union { u16 u[8]; int4 v; } o;
    o.u[0] = f2b_rn(a.x); o.u[1] = f2b_rn(a.y); o.u[2] = f2b_rn(a.z); o.u[3] = f2b_rn(a.w);
    o.u[4] = f2b_rn(b.x); o.u[5] = f2b_rn(b.y); o.u[6] = f2b_rn(b.z); o.u[7] = f2b_rn(b.w);
    *(int4*)(d) = o.v;
}

// ---------------------------------------------------------------------------
// Kernel P: fused prep.  blockIdx.x ranges:
//   [0,2048)      x fp32->bf16           (2048 elems/block)
//   [2048,2560)   Wo fp32->bf16
//   [2560,3328)   W transpose+convert -> Wt[3072][1024]
//   [3328,7424)   mask -> bitmask (16 wave-rows per block: 4 waves x 4 iters)
// ---------------------------------------------------------------------------
__global__ __launch_bounds__(256) void prep(
    const float* __restrict__ x, const float* __restrict__ Wq,
    const float* __restrict__ Wk, const float* __restrict__ Wv,
    const float* __restrict__ Wo, const int* __restrict__ mask,
    u16* __restrict__ xb, u16* __restrict__ Wt, u16* __restrict__ Wob,
    unsigned long long* __restrict__ bits)
{
    __shared__ u16 T[64 * 80];
    int bx = blockIdx.x;
    int tid = threadIdx.x;

    if (bx < 2048) {
        int i = bx * 2048 + tid * 8;
        cvt8(x + i, xb + i);
    } else if (bx < 2560) {
        int i = (bx - 2048) * 2048 + tid * 8;
        cvt8(Wo + i, Wob + i);
    } else if (bx < 3328) {
        int bx2 = bx - 2560;
        int e0 = (bx2 & 15) * 64;
        int ph = bx2 >> 4;              // 0..47
        int p = ph >> 4, h = ph & 15;
        const float* W = (p == 0 ? Wq : (p == 1 ? Wk : Wv)) + h * (EMB * HD);
        #pragma unroll
        for (int c = 0; c < 2; ++c) {
            int flat = c * 2048 + tid * 8;
            int r = flat >> 6;
            int d = flat & 63;
            cvt8(W + (size_t)(e0 + r) * HD + d, &T[r * 80 + d]);
        }
        __syncthreads();
        int d = tid >> 2;
        int ec = tid & 3;
        union { u16 u[16]; int4 v[2]; } tmp;
        #pragma unroll
        for (int i = 0; i < 16; ++i) tmp.u[i] = T[(ec * 16 + i) * 80 + d];
        u16* dst = Wt + ((size_t)(p * NH + h) * HD + d) * EMB + e0 + ec * 16;
        *(int4*)(dst) = tmp.v[0];
        *(int4*)(dst + 8) = tmp.v[1];
    } else {
        int base = (bx - 3328) * 16 + (tid >> 6) * 4;    // 4 waves x 4 rows
        int lane = tid & 63;
        #pragma unroll
        for (int i = 0; i < 4; ++i) {
            int gw = base + i;                            // 0..65535
            int m = mask[(size_t)gw * 64 + lane];
            unsigned long long bl = __ballot(m != 0);
            if (lane == 0) bits[gw] = bl;
        }
    }
}

// ---------------------------------------------------------------------------
// Kernel 1: fused QKV GEMM, m97 recipe (proven 48 us).  Grid (24 n, 32 m):
// linear id = n + 24*m -> the 32 blocks sharing one Wt2 n-panel sit at
// id-stride 24 (== 0 mod 8) -> same XCD -> panel re-reads are L2-local.
// C[4096][3072] = x @ Wt^T (+bias); 128x128 tile, BK=64.
// Q scaled by log2(e)/8.  V written transposed Vt[b,h][d][s].
// ---------------------------------------------------------------------------
__global__ __launch_bounds__(256) void qkv_gemm(
    const u16* __restrict__ x,    // bf16 [4096][1024]
    const u16* __restrict__ Wt2,  // bf16 [3072][1024]
    const float* __restrict__ bq, const float* __restrict__ bk, const float* __restrict__ bv,
    u16* __restrict__ Q, u16* __restrict__ K, u16* __restrict__ Vt)
{
    __shared__ u16 As[128 * 64];
    __shared__ u16 Bs[128 * 64];

    int n0 = blockIdx.x * 128;
    int m0 = blockIdx.y * 128;
    int tid = threadIdx.x;
    int w = tid >> 6, lane = tid & 63, quad = lane >> 4, ln = lane & 15;
    int wm = w & 1, wn = w >> 1;

    floatx4 acc[4][4] = {};

    for (int k0 = 0; k0 < EMB; k0 += 64) {
        __syncthreads();
        #pragma unroll
        for (int i = 0; i < 4; ++i) {
            int flat0 = i * 256 + (tid & 192);
            int flat = flat0 + lane;
            int r = flat >> 3;
            int c = ((flat & 7) ^ (r & 7)) * 8;
            gload_lds16(x   + (size_t)(m0 + r) * EMB + k0 + c, As + flat0 * 8);
            gload_lds16(Wt2 + (size_t)(n0 + r) * EMB + k0 + c, Bs + flat0 * 8);
        }
        __syncthreads();

        #pragma unroll
        for (int kk = 0; kk < 2; ++kk) {
            bf16x8 a[4], bf[4];
            #pragma unroll
            for (int mt = 0; mt < 4; ++mt)
                a[mt] = ldsfrag(As, wm * 64 + mt * 16 + ln, kk * 32 + quad * 8);
            #pragma unroll
            for (int nc = 0; nc < 4; ++nc)
                bf[nc] = ldsfrag(Bs, wn * 64 + nc * 16 + ln, kk * 32 + quad * 8);
            #pragma unroll
            for (int mt = 0; mt < 4; ++mt)
                #pragma unroll
                for (int nc = 0; nc < 4; ++nc)
                    acc[mt][nc] = __builtin_amdgcn_mfma_f32_16x16x32_bf16(a[mt], bf[nc], acc[mt][nc], 0, 0, 0);
        }
    }

    int p = n0 >> 10;
    const float* bias = (p == 0 ? bq : (p == 1 ? bk : bv));
    if (p < 2) {
        u16* Out = (p == 0) ? Q : K;
        float qs = (p == 0) ? 0.125f * 1.44269504f : 1.0f;   // fold 1/sqrt(64) and log2(e)
        #pragma unroll
        for (int nc = 0; nc < 4; ++nc) {
            int n = n0 + wn * 64 + nc * 16 + ln;
            int h = (n >> 6) & 15, d = n & 63;
            float bv_ = bias[n & 1023];
            #pragma unroll
            for (int mt = 0; mt < 4; ++mt) {
                #pragma unroll
                for (int reg = 0; reg < 4; ++reg) {
                    int m = m0 + wm * 64 + mt * 16 + quad * 4 + reg;
                    int b_ = m >> 10, s = m & 1023;
                    Out[((size_t)(b_ * NH + h) * SEQ + s) * HD + d] = f2b_rn((acc[mt][nc][reg] + bv_) * qs);
                }
            }
        }
    } else {
        #pragma unroll
        for (int nc = 0; nc < 4; ++nc) {
            int n = n0 + wn * 64 + nc * 16 + ln;
            int h = (n >> 6) & 15, d = n & 63;
            float bv_ = bias[n & 1023];
            #pragma unroll
            for (int mt = 0; mt < 4; ++mt) {
                int m = m0 + wm * 64 + mt * 16 + quad * 4;
                int b_ = m >> 10, s = m & 1023;
                union { u16 u[4]; uint2 v; } pk;
                #pragma unroll
                for (int reg = 0; reg < 4; ++reg)
                    pk.u[reg] = f2b_rn(acc[mt][nc][reg] + bv_);
                *(uint2*)&Vt[((size_t)(b_ * NH + h) * HD + d) * SEQ + s] = pk.v;
            }
        }
    }
}

// ---------------------------------------------------------------------------
// Kernel 2: flash attention v3 (best measured variant).  Grid (bh=64, qt=16):
// linear id = bh + 64*qt -> the 16 q-tile blocks sharing one (b,h)'s K/V sit
// at id-stride 64 (== 0 mod 8) -> same XCD -> K/V re-reads are L2-local.
// Block = 128 threads = 2 waves.  S computed TRANSPOSED (S^T = K Q^T):
// lane owns one softmax column, in-lane reductions, packed P writes.
// No online max: Q carries log2e/8, P = exp2(s); l from a ones-row in V.
// ---------------------------------------------------------------------------
__global__ __launch_bounds__(128) void attn(
    const u16* __restrict__ Q, const u16* __restrict__ K, const u16* __restrict__ Vt,
    const unsigned long long* __restrict__ bits,
    u16* __restrict__ Aout)         // bf16 [B][S][E]
{
    const int PP = 72;  // Ps row stride in u16 (144 B)
    __shared__ u16 Ks[64 * 64];
    __shared__ u16 Vs[80 * 64];     // rows 0..63 = V^T tile, row 64 = ones
    __shared__ u16 Ps[64 * PP];

    int bh = blockIdx.x;
    int q0 = blockIdx.y * 64;
    int b = bh >> 4, h = bh & 15;
    const u16* Qb = Q  + (size_t)bh * SEQ * HD;
    const u16* Kb = K  + (size_t)bh * SEQ * HD;
    const u16* Vb = Vt + (size_t)bh * HD * SEQ;   // [d][s]

    int tid = threadIdx.x;
    int w = tid >> 6, lane = tid & 63, quad = lane >> 4, ln = lane & 15;

    if (tid < 16) *(uint2*)&Vs[64 * 64 + tid * 4] = make_uint2(0x3F803F80u, 0x3F803F80u);

    bf16x8 qf[2][2];
    #pragma unroll
    for (int s = 0; s < 2; ++s) {
        const u16* qp = Qb + (size_t)(q0 + w * 32 + s * 16 + ln) * HD + quad * 8;
        union { int4 i; bf16x8 b; } c0, c1;
        c0.i = *(const int4*)(qp);
        c1.i = *(const int4*)(qp + 32);
        qf[s][0] = c0.b; qf[s][1] = c1.b;
    }

    floatx4 o[2][5] = {};   // [strip][dt], dt=4 is the l column

    for (int tt = 0; tt < SEQ / 64; ++tt) {
        int t0 = tt * 64;
        __syncthreads();
        #pragma unroll
        for (int i = 0; i < 4; ++i) {
            int flat0 = i * 128 + (tid & 64);
            int flat = flat0 + lane;
            int r = flat >> 3;
            int c = ((flat & 7) ^ (r & 7)) * 8;
            gload_lds16(Kb + (size_t)(t0 + r) * HD + c, Ks + flat0 * 8);
            gload_lds16(Vb + (size_t)r * SEQ + t0 + c, Vs + flat0 * 8);
        }
        __syncthreads();

        // S^T = K Q^T : rows t, cols m
        floatx4 sc[2][4] = {};
        #pragma unroll
        for (int kk = 0; kk < 2; ++kk) {
            bf16x8 kf[4];
            #pragma unroll
            for (int tb = 0; tb < 4; ++tb)
                kf[tb] = ldsfrag(Ks, tb * 16 + ln, kk * 32 + quad * 8);
            #pragma unroll
            for (int s = 0; s < 2; ++s)
                #pragma unroll
                for (int tb = 0; tb < 4; ++tb)
                    sc[s][tb] = __builtin_amdgcn_mfma_f32_16x16x32_bf16(kf[tb], qf[s][kk], sc[s][tb], 0, 0, 0);
        }

        #pragma unroll
        for (int s = 0; s < 2; ++s) {
            unsigned long long bm = bits[((size_t)b * SEQ + q0 + w * 32 + s * 16 + ln) * 16 + tt];
            if (__any(bm != ~0ull)) {
                #pragma unroll
                for (int tb = 0; tb < 4; ++tb)
                    #pragma unroll
                    for (int reg = 0; reg < 4; ++reg)
                        if (!((bm >> (tb * 16 + quad * 4 + reg)) & 1)) sc[s][tb][reg] = -1e30f;
            }
        }

        // P = exp2(S), pack 4 consecutive t -> b64 LDS write
        #pragma unroll
        for (int s = 0; s < 2; ++s) {
            int mrow = w * 32 + s * 16 + ln;
            #pragma unroll
            for (int tb = 0; tb < 4; ++tb) {
                union { float f; unsigned int i; } e0_, e1_, e2_, e3_;
                e0_.f = __builtin_amdgcn_exp2f(sc[s][tb][0]);
                e1_.f = __builtin_amdgcn_exp2f(sc[s][tb][1]);
                e2_.f = __builtin_amdgcn_exp2f(sc[s][tb][2]);
                e3_.f = __builtin_amdgcn_exp2f(sc[s][tb][3]);
                uint2 pk;
                pk.x = ((e0_.i + 0x8000u) >> 16) | ((e1_.i + 0x8000u) & 0xFFFF0000u);
                pk.y = ((e2_.i + 0x8000u) >> 16) | ((e3_.i + 0x8000u) & 0xFFFF0000u);
                *(uint2*)&Ps[mrow * PP + tb * 16 + quad * 4] = pk;
            }
        }

        // O += P V  (l accumulates in dt=4 via the ones row)
        #pragma unroll
        for (int kk = 0; kk < 2; ++kk) {
            bf16x8 vf[5];
            #pragma unroll
            for (int dt = 0; dt < 5; ++dt)
                vf[dt] = ldsfrag(Vs, dt * 16 + ln, kk * 32 + quad * 8);
            #pragma unroll
            for (int s = 0; s < 2; ++s) {
                bf16x8 pf = s2b(*(const short8*)&Ps[(w * 32 + s * 16 + ln) * PP + kk * 32 + quad * 8]);
                #pragma unroll
                for (int dt = 0; dt < 5; ++dt)
                    o[s][dt] = __builtin_amdgcn_mfma_f32_16x16x32_bf16(pf, vf[dt], o[s][dt], 0, 0, 0);
            }
        }
    }

    #pragma unroll
    for (int s = 0; s < 2; ++s) {
        #pragma unroll
        for (int reg = 0; reg < 4; ++reg) {
            float l = __shfl(o[s][4][reg], lane & 48, 64);
            float inv = 1.0f / l;
            int m = q0 + w * 32 + s * 16 + quad * 4 + reg;
            #pragma unroll
            for (int dt = 0; dt < 4; ++dt)
                Aout[((size_t)b * SEQ + m) * EMB + h * HD + dt * 16 + ln] = f2b_rn(o[s][dt][reg] * inv);
        }
    }
}

// ---------------------------------------------------------------------------
// Kernel 3: output projection.  64x128 tile, BK=64 single buffer, grid 512
// (2 blocks/CU).  id = m + 64*n -> same-m blocks (A-panel reuse) stride 64
// -> same XCD.  Out[4096][1024] fp32.
// ---------------------------------------------------------------------------
__global__ __launch_bounds__(256) void out_proj(
    const u16* __restrict__ A,    // bf16 [4096][1024]
    const u16* __restrict__ Wo,   // bf16 [1024][1024] (n,k)
    const float* __restrict__ bo,
    float* __restrict__ Out)
{
    __shared__ u16 As[64 * 64];
    __shared__ u16 Bs[128 * 64];

    int m0 = blockIdx.x * 64;
    int n0 = blockIdx.y * 128;
    int tid = threadIdx.x;
    int w = tid >> 6, lane = tid & 63, quad = lane >> 4, ln = lane & 15;
    int wm = w & 1, wn = w >> 1;

    floatx4 acc[2][4] = {};

    for (int k0 = 0; k0 < EMB; k0 += 64) {
        __syncthreads();
        #pragma unroll
        for (int i = 0; i < 2; ++i) {
            int flat0 = i * 256 + (tid & 192);
            int flat = flat0 + lane;
            int r = flat >> 3;                   // 0..63
            int c = ((flat & 7) ^ (r & 7)) * 8;
            gload_lds16(A + (size_t)(m0 + r) * EMB + k0 + c, As + flat0 * 8);
        }
        #pragma unroll
        for (int i = 0; i < 4; ++i) {
            int flat0 = i * 256 + (tid & 192);
            int flat = flat0 + lane;
            int r = flat >> 3;                   // 0..127
            int c = ((flat & 7) ^ (r & 7)) * 8;
            gload_lds16(Wo + (size_t)(n0 + r) * EMB + k0 + c, Bs + flat0 * 8);
        }
        __syncthreads();

        #pragma unroll
        for (int kk = 0; kk < 2; ++kk) {
            bf16x8 a[2], bfr[4];
            #pragma unroll
            for (int mt = 0; mt < 2; ++mt)
                a[mt] = ldsfrag(As, wm * 32 + mt * 16 + ln, kk * 32 + quad * 8);
            #pragma unroll
            for (int nc = 0; nc < 4; ++nc)
                bfr[nc] = ldsfrag(Bs, wn * 64 + nc * 16 + ln, kk * 32 + quad * 8);
            #pragma unroll
            for (int mt = 0; mt < 2; ++mt)
                #pragma unroll
                for (int nc = 0; nc < 4; ++nc)
                    acc[mt][nc] = __builtin_amdgcn_mfma_f32_16x16x32_bf16(a[mt], bfr[nc], acc[mt][nc], 0, 0, 0);
        }
    }

    #pragma unroll
    for (int nc = 0; nc < 4; ++nc) {
        int n = n0 + wn * 64 + nc * 16 + ln;
        float bb = bo[n];
        #pragma unroll
        for (int mt = 0; mt < 2; ++mt) {
            #pragma unroll
            for (int reg = 0; reg < 4; ++reg) {
                int m = m0 + wm * 32 + mt * 16 + quad * 4 + reg;
                Out[(size_t)m * EMB + n] = acc[mt][nc][reg] + bb;
            }
        }
    }
}

// ---------------------------------------------------------------------------
extern "C" void kernel_launch(void* const* d_in, const int* in_sizes, int n_in,
                              void* d_out, int out_size, void* d_ws, size_t ws_size,
                              hipStream_t stream) {
    const float* x  = (const float*)d_in[0];
    const int*   mk = (const int*)d_in[1];
    const float* Wq = (const float*)d_in[2];
    const float* bq = (const float*)d_in[3];
    const float* Wk = (const float*)d_in[4];
    const float* bk = (const float*)d_in[5];
    const float* Wv = (const float*)d_in[6];
    const float* bv = (const float*)d_in[7];
    const float* Wo = (const float*)d_in[8];
    const float* bo = (const float*)d_in[9];
    float* out = (float*)d_out;

    const size_t MB = 1u << 20;
    char* ws = (char*)d_ws;
    u16* xb  = (u16*)ws;                                   // [ 0, 8M)
    u16* Wt  = (u16*)(ws + 8 * MB);                        // [ 8,14M)
    u16* Wob = (u16*)(ws + 14 * MB);                       // [14,16M)
    unsigned long long* bits = (unsigned long long*)(ws + 16 * MB); // [16,16.5M)
    u16* Qw  = (u16*)(ws + 16 * MB + 512 * 1024);          // [16.5,24.5M)
    u16* Kw  = (u16*)(ws + 24 * MB + 512 * 1024);          // [24.5,32.5M)
    u16* Vtw = (u16*)(ws + 32 * MB + 512 * 1024);          // [32.5,40.5M)
    u16* Ao  = xb;                                         // reuse: xb dead after qkv

    prep<<<7424, 256, 0, stream>>>(x, Wq, Wk, Wv, Wo, mk, xb, Wt, Wob, bits);
    qkv_gemm<<<dim3(3 * EMB / 128, (NB * SEQ) / 128), 256, 0, stream>>>(
        xb, Wt, bq, bk, bv, Qw, Kw, Vtw);
    attn<<<dim3(NB * NH, SEQ / 64), 128, 0, stream>>>(Qw, Kw, Vtw, bits, Ao);
    out_proj<<<dim3((NB * SEQ) / 64, EMB / 128), 256, 0, stream>>>(Ao, Wob, bo, out);
}

// Round 12
// 198.033 us; speedup vs baseline: 1.1645x; 1.0142x over previous
//
#include <hip/hip_runtime.h>
#include <hip/hip_bf16.h>

#define NB 4       // batch
#define SEQ 1024
#define EMB 1024
#define NH 16
#define HD 64

typedef unsigned short u16;
typedef __attribute__((ext_vector_type(8))) __bf16 bf16x8;
typedef __attribute__((ext_vector_type(8))) short short8;
typedef __attribute__((ext_vector_type(4))) float floatx4;

// fp32 -> bf16 round-to-nearest-even
__device__ inline u16 f2b_rn(float f) {
    union { float f; unsigned int i; } x; x.f = f;
    unsigned int r = (x.i + 0x7FFFu + ((x.i >> 16) & 1u)) >> 16;
    return (u16)r;
}
__device__ inline bf16x8 s2b(short8 v) {
    union { short8 s; bf16x8 b; } x; x.s = v; return x.b;
}

// async global->LDS, 16 B per lane.  LDS dest = wave-uniform base + lane*16.
__device__ inline void gload_lds16(const void* g, void* l) {
    __builtin_amdgcn_global_load_lds(
        (const __attribute__((address_space(1))) void*)g,
        (__attribute__((address_space(3))) void*)l, 16, 0, 0);
}

// XOR-swizzled fragment read from an unpadded [rows][64] u16 LDS buffer.
// One row = 128 B = all 32 banks; (r&7) XOR spreads 16-lane b128 reads.
__device__ inline bf16x8 ldsfrag(const u16* base, int r, int c) {
    return s2b(*(const short8*)&base[r * 64 + (c ^ ((r & 7) * 8))]);
}

__device__ inline void cvt8(const float* __restrict__ s, u16* __restrict__ d) {
    float4 a = *(const float4*)(s);
    float4 b = *(const float4*)(s + 4);
    union { u16 u[8]; int4 v; } o;
    o.u[0] = f2b_rn(a.x); o.u[1] = f2b_rn(a.y); o.u[2] = f2b_rn(a.z); o.u[3] = f2b_rn(a.w);
    o.u[4] = f2b_rn(b.x); o.u[5] = f2b_rn(b.y); o.u[6] = f2b_rn(b.z); o.u[7] = f2b_rn(b.w);
    *(int4*)(d) = o.v;
}

// ---------------------------------------------------------------------------
// Kernel P: prep — only the qkv prerequisites.  blockIdx.x ranges:
//   [0,512)     x fp32->bf16   (4 x 2048 elems per block)
//   [512,1280)  W transpose+convert -> Wt[3072][1024]
// ---------------------------------------------------------------------------
__global__ __launch_bounds__(256) void prep(
    const float* __restrict__ x, const float* __restrict__ Wq,
    const float* __restrict__ Wk, const float* __restrict__ Wv,
    u16* __restrict__ xb, u16* __restrict__ Wt)
{
    __shared__ u16 T[64 * 80];
    int bx = blockIdx.x;
    int tid = threadIdx.x;

    if (bx < 512) {
        #pragma unroll
        for (int c = 0; c < 4; ++c) {
            int i = (bx * 4 + c) * 2048 + tid * 8;
            cvt8(x + i, xb + i);
        }
    } else {
        int bx2 = bx - 512;
        int e0 = (bx2 & 15) * 64;
        int ph = bx2 >> 4;              // 0..47
        int p = ph >> 4, h = ph & 15;
        const float* W = (p == 0 ? Wq : (p == 1 ? Wk : Wv)) + h * (EMB * HD);
        #pragma unroll
        for (int c = 0; c < 2; ++c) {
            int flat = c * 2048 + tid * 8;
            int r = flat >> 6;
            int d = flat & 63;
            cvt8(W + (size_t)(e0 + r) * HD + d, &T[r * 80 + d]);
        }
        __syncthreads();
        int d = tid >> 2;
        int ec = tid & 3;
        union { u16 u[16]; int4 v[2]; } tmp;
        #pragma unroll
        for (int i = 0; i < 16; ++i) tmp.u[i] = T[(ec * 16 + i) * 80 + d];
        u16* dst = Wt + ((size_t)(p * NH + h) * HD + d) * EMB + e0 + ec * 16;
        *(int4*)(dst) = tmp.v[0];
        *(int4*)(dst + 8) = tmp.v[1];
    }
}

// ---------------------------------------------------------------------------
// Kernel 1: fused QKV GEMM (m97 recipe) + FINE-GRAINED aux tail blocks.
// gid < 768 :      GEMM. n0=(gid%24)*128, m0=(gid/24)*128.  C = x @ Wt^T
//                  (+bias); Q scaled by log2(e)/8; V transposed Vt[b,h][d][s].
// gid 768..1279 :  Wo fp32->bf16 (2048 elems/block — 1 cvt8 per thread)
// gid 1280..5375:  mask ballots — 4096 blocks x 16 rows (4 rows/wave),
//                  covering ALL 65536 (b,row,tile) entries  [r11 bug: had
//                  only 1024 blocks -> 3/4 of bits left poisoned]
// ---------------------------------------------------------------------------
__global__ __launch_bounds__(256) void qkv_gemm(
    const u16* __restrict__ x,    // bf16 [4096][1024]
    const u16* __restrict__ Wt2,  // bf16 [3072][1024]
    const float* __restrict__ bq, const float* __restrict__ bk, const float* __restrict__ bv,
    const float* __restrict__ Wo, const int* __restrict__ mask,
    u16* __restrict__ Q, u16* __restrict__ K, u16* __restrict__ Vt,
    u16* __restrict__ Wob, unsigned long long* __restrict__ bits)
{
    __shared__ u16 As[128 * 64];
    __shared__ u16 Bs[128 * 64];

    int gid = blockIdx.x;
    int tid = threadIdx.x;

    if (gid >= 768) {
        if (gid < 1280) {                 // Wo convert: 512 blocks x 2048 elems
            int i = (gid - 768) * 2048 + tid * 8;
            cvt8(Wo + i, Wob + i);
        } else {                          // mask ballots: 4096 blocks x 16 rows
            int base = (gid - 1280) * 16 + (tid >> 6) * 4;
            int lane = tid & 63;
            #pragma unroll
            for (int i = 0; i < 4; ++i) {
                int gw = base + i;        // 0..65535
                int m = mask[(size_t)gw * 64 + lane];
                unsigned long long bl = __ballot(m != 0);
                if (lane == 0) bits[gw] = bl;
            }
        }
        return;
    }

    int n0 = (gid % 24) * 128;
    int m0 = (gid / 24) * 128;
    int w = tid >> 6, lane = tid & 63, quad = lane >> 4, ln = lane & 15;
    int wm = w & 1, wn = w >> 1;

    floatx4 acc[4][4] = {};

    for (int k0 = 0; k0 < EMB; k0 += 64) {
        __syncthreads();
        #pragma unroll
        for (int i = 0; i < 4; ++i) {
            int flat0 = i * 256 + (tid & 192);
            int flat = flat0 + lane;
            int r = flat >> 3;
            int c = ((flat & 7) ^ (r & 7)) * 8;
            gload_lds16(x   + (size_t)(m0 + r) * EMB + k0 + c, As + flat0 * 8);
            gload_lds16(Wt2 + (size_t)(n0 + r) * EMB + k0 + c, Bs + flat0 * 8);
        }
        __syncthreads();

        #pragma unroll
        for (int kk = 0; kk < 2; ++kk) {
            bf16x8 a[4], bf[4];
            #pragma unroll
            for (int mt = 0; mt < 4; ++mt)
                a[mt] = ldsfrag(As, wm * 64 + mt * 16 + ln, kk * 32 + quad * 8);
            #pragma unroll
            for (int nc = 0; nc < 4; ++nc)
                bf[nc] = ldsfrag(Bs, wn * 64 + nc * 16 + ln, kk * 32 + quad * 8);
            #pragma unroll
            for (int mt = 0; mt < 4; ++mt)
                #pragma unroll
                for (int nc = 0; nc < 4; ++nc)
                    acc[mt][nc] = __builtin_amdgcn_mfma_f32_16x16x32_bf16(a[mt], bf[nc], acc[mt][nc], 0, 0, 0);
        }
    }

    int p = n0 >> 10;
    const float* bias = (p == 0 ? bq : (p == 1 ? bk : bv));
    if (p < 2) {
        u16* Out = (p == 0) ? Q : K;
        float qs = (p == 0) ? 0.125f * 1.44269504f : 1.0f;   // fold 1/sqrt(64) and log2(e)
        #pragma unroll
        for (int nc = 0; nc < 4; ++nc) {
            int n = n0 + wn * 64 + nc * 16 + ln;
            int h = (n >> 6) & 15, d = n & 63;
            float bv_ = bias[n & 1023];
            #pragma unroll
            for (int mt = 0; mt < 4; ++mt) {
                #pragma unroll
                for (int reg = 0; reg < 4; ++reg) {
                    int m = m0 + wm * 64 + mt * 16 + quad * 4 + reg;
                    int b_ = m >> 10, s = m & 1023;
                    Out[((size_t)(b_ * NH + h) * SEQ + s) * HD + d] = f2b_rn((acc[mt][nc][reg] + bv_) * qs);
                }
            }
        }
    } else {
        #pragma unroll
        for (int nc = 0; nc < 4; ++nc) {
            int n = n0 + wn * 64 + nc * 16 + ln;
            int h = (n >> 6) & 15, d = n & 63;
            float bv_ = bias[n & 1023];
            #pragma unroll
            for (int mt = 0; mt < 4; ++mt) {
                int m = m0 + wm * 64 + mt * 16 + quad * 4;
                int b_ = m >> 10, s = m & 1023;
                union { u16 u[4]; uint2 v; } pk;
                #pragma unroll
                for (int reg = 0; reg < 4; ++reg)
                    pk.u[reg] = f2b_rn(acc[mt][nc][reg] + bv_);
                *(uint2*)&Vt[((size_t)(b_ * NH + h) * HD + d) * SEQ + s] = pk.v;
            }
        }
    }
}

// ---------------------------------------------------------------------------
// Kernel 2: flash attention v3.  Grid (bh=64, qt=16).  Block = 128 thr =
// 2 waves.  S computed TRANSPOSED (S^T = K Q^T): lane owns one softmax
// column, in-lane reductions, packed P writes.  No online max: Q carries
// log2e/8, P = exp2(s); l from a ones-row appended to V.
// ---------------------------------------------------------------------------
__global__ __launch_bounds__(128) void attn(
    const u16* __restrict__ Q, const u16* __restrict__ K, const u16* __restrict__ Vt,
    const unsigned long long* __restrict__ bits,
    u16* __restrict__ Aout)         // bf16 [B][S][E]
{
    const int PP = 72;  // Ps row stride in u16 (144 B)
    __shared__ u16 Ks[64 * 64];
    __shared__ u16 Vs[80 * 64];     // rows 0..63 = V^T tile, row 64 = ones
    __shared__ u16 Ps[64 * PP];

    int bh = blockIdx.x;
    int q0 = blockIdx.y * 64;
    int b = bh >> 4, h = bh & 15;
    const u16* Qb = Q  + (size_t)bh * SEQ * HD;
    const u16* Kb = K  + (size_t)bh * SEQ * HD;
    const u16* Vb = Vt + (size_t)bh * HD * SEQ;   // [d][s]

    int tid = threadIdx.x;
    int w = tid >> 6, lane = tid & 63, quad = lane >> 4, ln = lane & 15;

    if (tid < 16) *(uint2*)&Vs[64 * 64 + tid * 4] = make_uint2(0x3F803F80u, 0x3F803F80u);

    bf16x8 qf[2][2];
    #pragma unroll
    for (int s = 0; s < 2; ++s) {
        const u16* qp = Qb + (size_t)(q0 + w * 32 + s * 16 + ln) * HD + quad * 8;
        union { int4 i; bf16x8 b; } c0, c1;
        c0.i = *(const int4*)(qp);
        c1.i = *(const int4*)(qp + 32);
        qf[s][0] = c0.b; qf[s][1] = c1.b;
    }

    floatx4 o[2][5] = {};   // [strip][dt], dt=4 is the l column

    for (int tt = 0; tt < SEQ / 64; ++tt) {
        int t0 = tt * 64;
        __syncthreads();
        #pragma unroll
        for (int i = 0; i < 4; ++i) {
            int flat0 = i * 128 + (tid & 64);
            int flat = flat0 + lane;
            int r = flat >> 3;
            int c = ((flat & 7) ^ (r & 7)) * 8;
            gload_lds16(Kb + (size_t)(t0 + r) * HD + c, Ks + flat0 * 8);
            gload_lds16(Vb + (size_t)r * SEQ + t0 + c, Vs + flat0 * 8);
        }
        __syncthreads();

        // S^T = K Q^T : rows t, cols m
        floatx4 sc[2][4] = {};
        #pragma unroll
        for (int kk = 0; kk < 2; ++kk) {
            bf16x8 kf[4];
            #pragma unroll
            for (int tb = 0; tb < 4; ++tb)
                kf[tb] = ldsfrag(Ks, tb * 16 + ln, kk * 32 + quad * 8);
            #pragma unroll
            for (int s = 0; s < 2; ++s)
                #pragma unroll
                for (int tb = 0; tb < 4; ++tb)
                    sc[s][tb] = __builtin_amdgcn_mfma_f32_16x16x32_bf16(kf[tb], qf[s][kk], sc[s][tb], 0, 0, 0);
        }

        #pragma unroll
        for (int s = 0; s < 2; ++s) {
            unsigned long long bm = bits[((size_t)b * SEQ + q0 + w * 32 + s * 16 + ln) * 16 + tt];
            if (__any(bm != ~0ull)) {
                #pragma unroll
                for (int tb = 0; tb < 4; ++tb)
                    #pragma unroll
                    for (int reg = 0; reg < 4; ++reg)
                        if (!((bm >> (tb * 16 + quad * 4 + reg)) & 1)) sc[s][tb][reg] = -1e30f;
            }
        }

        // P = exp2(S), pack 4 consecutive t -> b64 LDS write
        #pragma unroll
        for (int s = 0; s < 2; ++s) {
            int mrow = w * 32 + s * 16 + ln;
            #pragma unroll
            for (int tb = 0; tb < 4; ++tb) {
                union { float f; unsigned int i; } e0_, e1_, e2_, e3_;
                e0_.f = __builtin_amdgcn_exp2f(sc[s][tb][0]);
                e1_.f = __builtin_amdgcn_exp2f(sc[s][tb][1]);
                e2_.f = __builtin_amdgcn_exp2f(sc[s][tb][2]);
                e3_.f = __builtin_amdgcn_exp2f(sc[s][tb][3]);
                uint2 pk;
                pk.x = ((e0_.i + 0x8000u) >> 16) | ((e1_.i + 0x8000u) & 0xFFFF0000u);
                pk.y = ((e2_.i + 0x8000u) >> 16) | ((e3_.i + 0x8000u) & 0xFFFF0000u);
                *(uint2*)&Ps[mrow * PP + tb * 16 + quad * 4] = pk;
            }
        }

        // O += P V  (l accumulates in dt=4 via the ones row)
        #pragma unroll
        for (int kk = 0; kk < 2; ++kk) {
            bf16x8 vf[5];
            #pragma unroll
            for (int dt = 0; dt < 5; ++dt)
                vf[dt] = ldsfrag(Vs, dt * 16 + ln, kk * 32 + quad * 8);
            #pragma unroll
            for (int s = 0; s < 2; ++s) {
                bf16x8 pf = s2b(*(const short8*)&Ps[(w * 32 + s * 16 + ln) * PP + kk * 32 + quad * 8]);
                #pragma unroll
                for (int dt = 0; dt < 5; ++dt)
                    o[s][dt] = __builtin_amdgcn_mfma_f32_16x16x32_bf16(pf, vf[dt], o[s][dt], 0, 0, 0);
            }
        }
    }

    #pragma unroll
    for (int s = 0; s < 2; ++s) {
        #pragma unroll
        for (int reg = 0; reg < 4; ++reg) {
            float l = __shfl(o[s][4][reg], lane & 48, 64);
            float inv = 1.0f / l;
            int m = q0 + w * 32 + s * 16 + quad * 4 + reg;
            #pragma unroll
            for (int dt = 0; dt < 4; ++dt)
                Aout[((size_t)b * SEQ + m) * EMB + h * HD + dt * 16 + ln] = f2b_rn(o[s][dt][reg] * inv);
        }
    }
}

// ---------------------------------------------------------------------------
// Kernel 3: output projection.  64x128 tile, BK=64 single buffer, grid 512
// (2 blocks/CU).  Out[4096][1024] fp32.
// ---------------------------------------------------------------------------
__global__ __launch_bounds__(256) void out_proj(
    const u16* __restrict__ A,    // bf16 [4096][1024]
    const u16* __restrict__ Wo,   // bf16 [1024][1024] (n,k)
    const float* __restrict__ bo,
    float* __restrict__ Out)
{
    __shared__ u16 As[64 * 64];
    __shared__ u16 Bs[128 * 64];

    int m0 = blockIdx.x * 64;
    int n0 = blockIdx.y * 128;
    int tid = threadIdx.x;
    int w = tid >> 6, lane = tid & 63, quad = lane >> 4, ln = lane & 15;
    int wm = w & 1, wn = w >> 1;

    floatx4 acc[2][4] = {};

    for (int k0 = 0; k0 < EMB; k0 += 64) {
        __syncthreads();
        #pragma unroll
        for (int i = 0; i < 2; ++i) {
            int flat0 = i * 256 + (tid & 192);
            int flat = flat0 + lane;
            int r = flat >> 3;                   // 0..63
            int c = ((flat & 7) ^ (r & 7)) * 8;
            gload_lds16(A + (size_t)(m0 + r) * EMB + k0 + c, As + flat0 * 8);
        }
        #pragma unroll
        for (int i = 0; i < 4; ++i) {
            int flat0 = i * 256 + (tid & 192);
            int flat = flat0 + lane;
            int r = flat >> 3;                   // 0..127
            int c = ((flat & 7) ^ (r & 7)) * 8;
            gload_lds16(Wo + (size_t)(n0 + r) * EMB + k0 + c, Bs + flat0 * 8);
        }
        __syncthreads();

        #pragma unroll
        for (int kk = 0; kk < 2; ++kk) {
            bf16x8 a[2], bfr[4];
            #pragma unroll
            for (int mt = 0; mt < 2; ++mt)
                a[mt] = ldsfrag(As, wm * 32 + mt * 16 + ln, kk * 32 + quad * 8);
            #pragma unroll
            for (int nc = 0; nc < 4; ++nc)
                bfr[nc] = ldsfrag(Bs, wn * 64 + nc * 16 + ln, kk * 32 + quad * 8);
            #pragma unroll
            for (int mt = 0; mt < 2; ++mt)
                #pragma unroll
                for (int nc = 0; nc < 4; ++nc)
                    acc[mt][nc] = __builtin_amdgcn_mfma_f32_16x16x32_bf16(a[mt], bfr[nc], acc[mt][nc], 0, 0, 0);
        }
    }

    #pragma unroll
    for (int nc = 0; nc < 4; ++nc) {
        int n = n0 + wn * 64 + nc * 16 + ln;
        float bb = bo[n];
        #pragma unroll
        for (int mt = 0; mt < 2; ++mt) {
            #pragma unroll
            for (int reg = 0; reg < 4; ++reg) {
                int m = m0 + wm * 32 + mt * 16 + quad * 4 + reg;
                Out[(size_t)m * EMB + n] = acc[mt][nc][reg] + bb;
            }
        }
    }
}

// ---------------------------------------------------------------------------
extern "C" void kernel_launch(void* const* d_in, const int* in_sizes, int n_in,
                              void* d_out, int out_size, void* d_ws, size_t ws_size,
                              hipStream_t stream) {
    const float* x  = (const float*)d_in[0];
    const int*   mk = (const int*)d_in[1];
    const float* Wq = (const float*)d_in[2];
    const float* bq = (const float*)d_in[3];
    const float* Wk = (const float*)d_in[4];
    const float* bk = (const float*)d_in[5];
    const float* Wv = (const float*)d_in[6];
    const float* bv = (const float*)d_in[7];
    const float* Wo = (const float*)d_in[8];
    const float* bo = (const float*)d_in[9];
    float* out = (float*)d_out;

    const size_t MB = 1u << 20;
    char* ws = (char*)d_ws;
    u16* xb  = (u16*)ws;                                   // [ 0, 8M)
    u16* Wt  = (u16*)(ws + 8 * MB);                        // [ 8,14M)
    u16* Wob = (u16*)(ws + 14 * MB);                       // [14,16M)
    unsigned long long* bits = (unsigned long long*)(ws + 16 * MB); // [16,16.5M)
    u16* Qw  = (u16*)(ws + 16 * MB + 512 * 1024);          // [16.5,24.5M)
    u16* Kw  = (u16*)(ws + 24 * MB + 512 * 1024);          // [24.5,32.5M)
    u16* Vtw = (u16*)(ws + 32 * MB + 512 * 1024);          // [32.5,40.5M)
    u16* Ao  = xb;                                         // reuse: xb dead after qkv

    prep<<<1280, 256, 0, stream>>>(x, Wq, Wk, Wv, xb, Wt);
    qkv_gemm<<<5376, 256, 0, stream>>>(
        xb, Wt, bq, bk, bv, Wo, mk, Qw, Kw, Vtw, Wob, bits);
    attn<<<dim3(NB * NH, SEQ / 64), 128, 0, stream>>>(Qw, Kw, Vtw, bits, Ao);
    out_proj<<<dim3((NB * SEQ) / 64, EMB / 128), 256, 0, stream>>>(Ao, Wob, bo, out);
}